// Round 8
// baseline (108.326 us; speedup 1.0000x reference)
//
#include <hip/hip_runtime.h>
#include <math.h>

// Problem constants (from reference)
constexpr int kB = 256, kT = 8, kS = 200, kR = 8, kD = 64, kF = 20;

// w_k = 2*pi * (k * 0.5/(F-1)) * t = k * (pi/19) * t
constexpr float kW1 = 3.14159265358979323846f / 19.0f;

// ---------------------------------------------------------------------------
// Kernel 1: decay[b][r][s] (T-independent -> computed ONCE per b, not per
// (b,t): removes 8x-redundant work and ~80 LDS-b128/wave from the main
// kernel's critical pipe). d_ws is free: harness poison-fill runs regardless.
//   grid 256 (1 block/b), tid = r*32+j. fr/fi register-cached (40 VGPR).
//   cos/sin via angle-addition recurrence from one __sincosf (k<=19, error
//   ~k*eps -> negligible vs 1.6e-5 threshold).
//   Stores coalesced (consecutive j -> consecutive s).
// ---------------------------------------------------------------------------
__global__ __launch_bounds__(256) void decay_kernel(
    const float* __restrict__ dt,   // [B,S]
    const float* __restrict__ fr,   // [R,F]
    const float* __restrict__ fi,   // [R,F]
    const int*   __restrict__ vm,   // [B,S]
    float* __restrict__ dec)        // [B,R,S] (d_ws)
{
    const int b = blockIdx.x;
    const int tid = threadIdx.x;
    const int r = tid >> 5, j = tid & 31;

    // register-cache this r's tables (16B-aligned: 20 floats = 80B = 5x16B)
    float frr[kF], fir[kF];
    {
        const float4* f4 = (const float4*)(fr + r * kF);
        const float4* g4 = (const float4*)(fi + r * kF);
#pragma unroll
        for (int c = 0; c < 5; ++c) {
            float4 a = f4[c], g = g4[c];
            frr[4 * c + 0] = a.x; frr[4 * c + 1] = a.y;
            frr[4 * c + 2] = a.z; frr[4 * c + 3] = a.w;
            fir[4 * c + 0] = g.x; fir[4 * c + 1] = g.y;
            fir[4 * c + 2] = g.z; fir[4 * c + 3] = g.w;
        }
    }

#pragma unroll
    for (int it = 0; it < 7; ++it) {
        const int s = j + 32 * it;
        if (s < kS) {
            const float tt = dt[b * kS + s];
            const bool valid = vm[b * kS + s] != 0;
            float s1, c1;
            __sincosf(kW1 * tt, &s1, &c1);
            // k=0: cos=1,sin=0 -> frr[0]; k=1 direct; k>=2 recurrence
            float ck = c1, sk = s1;
            float acc = frr[0] + c1 * frr[1] - s1 * fir[1];
#pragma unroll
            for (int k = 2; k < kF; ++k) {
                float cn = ck * c1 - sk * s1;
                float sn = sk * c1 + ck * s1;
                ck = cn; sk = sn;
                acc += ck * frr[k] - sk * fir[k];
            }
            float v = fminf(fmaxf(acc * (1.0f / (2.0f * kF)), 0.f), 1.f);
            dec[(b * kR + r) * kS + s] = valid ? v : 0.f;
        }
    }
}

// ---------------------------------------------------------------------------
// Kernel 2: one block per (b,t), 256 threads = 4 waves, grid 2048.
// b = o%256 -> all 8 t-blocks of a b land on one XCD (seq L2-resident).
//   P0 : ri[r][d] = (rel+tv)*target -> LDS
//   P1 : thread s (<200): att_raw[r][s] = seq[b,s,:].ri[r,:]  (. : -inf)
//        (128 broadcast ds_read_b128/wave: uniqueness-optimal for ri)
//   P2 : wave w, r=2w,2w+1: softmax over s (shfl reduce) * dec (GLOBAL,
//        coalesced) -> att_final kept in REGISTERS pa[h][m] (lane = s%64)
//   P3 : no LDS: fully-unrolled s-loop, att broadcast via v_readlane
//        (VALU pipe, compile-time lane), seq coalesced (lane=d);
//        wave w writes out rows r=2w,2w+1 directly. P4 eliminated.
// NOTES:
//  - global `att - att.max()` is shift-invariant under softmax -> omitted.
//  - LDS now 8.4 KB, 2 barriers total.
//  - plain __launch_bounds__(256): R5/R6 showed min-waves arg w pins
//    VGPR ~ 256/w and forces catastrophic spills.
// ---------------------------------------------------------------------------
__global__ __launch_bounds__(256) void rda_main(
    const float* __restrict__ seq,    // [B,S,D]
    const float* __restrict__ target, // [B,T,D]
    const float* __restrict__ tv,     // [B,T,R,D]
    const int*   __restrict__ vm,     // [B,S]
    const float* __restrict__ rel,    // [R,D]
    const float* __restrict__ dec,    // [B,R,S] (d_ws)
    float* __restrict__ out)          // [B,T,R,D]
{
    __shared__ float ri[kR * kD];     // 2 KB
    __shared__ float att[kR][kS];     // 6.4 KB (row stride 200w -> +8 banks/row)

    const int o = blockIdx.x;
    const int b = o & 255, t = o >> 8;
    const int bt = b * kT + t;
    const int tid = threadIdx.x, wave = tid >> 6, lane = tid & 63;

    // ---- P0: ri
    {
        const float* tvb = tv + (size_t)bt * kR * kD;
        const float* tgb = target + (size_t)bt * kD;
        for (int idx = tid; idx < kR * kD; idx += 256)
            ri[idx] = (rel[idx] + tvb[idx]) * tgb[idx & 63];
    }
    __syncthreads();

    // ---- P1: raw scores (thread = s)
    if (tid < kS) {
        const int s = tid;
        const bool valid = vm[b * kS + s] != 0;
        const float4* seqrow = (const float4*)(seq + (size_t)(b * kS + s) * kD);
        float a[kR];
#pragma unroll
        for (int r = 0; r < kR; ++r) a[r] = 0.f;
#pragma unroll
        for (int uu = 0; uu < kD / 4; ++uu) {
            float4 sv = seqrow[uu];
#pragma unroll
            for (int r = 0; r < kR; ++r) {
                float4 rv = ((const float4*)(ri + r * kD))[uu];
                a[r] += sv.x * rv.x + sv.y * rv.y + sv.z * rv.z + sv.w * rv.w;
            }
        }
#pragma unroll
        for (int r = 0; r < kR; ++r)
            att[r][s] = valid ? a[r] : -INFINITY;
    }
    __syncthreads();

    // ---- P2: masked softmax * decay -> registers (wave w -> r=2w,2w+1)
    float pa[2][4];
#pragma unroll
    for (int h = 0; h < 2; ++h) {
        const int r = 2 * wave + h;
        const float* row = &att[r][0];
        float a0 = row[lane];
        float a1 = row[lane + 64];
        float a2 = row[lane + 128];
        float a3 = (lane < kS - 192) ? row[lane + 192] : -INFINITY;
        float m = fmaxf(fmaxf(a0, a1), fmaxf(a2, a3));
#pragma unroll
        for (int off = 32; off; off >>= 1) m = fmaxf(m, __shfl_xor(m, off));
        float e0 = __expf(a0 - m), e1 = __expf(a1 - m), e2 = __expf(a2 - m);
        float e3 = (lane < kS - 192) ? __expf(a3 - m) : 0.f;
        float ssum = e0 + e1 + e2 + e3;
#pragma unroll
        for (int off = 32; off; off >>= 1) ssum += __shfl_xor(ssum, off);
        const float inv = 1.0f / ssum;
        const float* dg = dec + ((size_t)b * kR + r) * kS;
        pa[h][0] = e0 * inv * dg[lane];
        pa[h][1] = e1 * inv * dg[lane + 64];
        pa[h][2] = e2 * inv * dg[lane + 128];
        pa[h][3] = (lane < kS - 192) ? e3 * inv * dg[lane + 192] : 0.f;
    }

    // ---- P3: context, zero LDS. att[r][s] lives in lane (s&63), slot (s>>6);
    // v_readlane broadcasts it (s fully unrolled -> constant lane index).
    {
        float acc0 = 0.f, acc1 = 0.f;
        const float* sq = seq + (size_t)b * kS * kD + lane;
#pragma unroll
        for (int s = 0; s < kS; ++s) {
            float sv = sq[(size_t)s * kD];
            float a0 = __int_as_float(
                __builtin_amdgcn_readlane(__float_as_int(pa[0][s >> 6]), s & 63));
            float a1 = __int_as_float(
                __builtin_amdgcn_readlane(__float_as_int(pa[1][s >> 6]), s & 63));
            acc0 += sv * a0;
            acc1 += sv * a1;
        }
        float* ob = out + (size_t)bt * kR * kD;
        ob[(2 * wave + 0) * kD + lane] = acc0;
        ob[(2 * wave + 1) * kD + lane] = acc1;
    }
}

extern "C" void kernel_launch(void* const* d_in, const int* in_sizes, int n_in,
                              void* d_out, int out_size, void* d_ws, size_t ws_size,
                              hipStream_t stream) {
    const float* seq    = (const float*)d_in[0];
    const float* dt     = (const float*)d_in[1];
    const float* target = (const float*)d_in[2];
    const float* tv     = (const float*)d_in[3];
    const int*   vm     = (const int*)  d_in[4];
    const float* rel    = (const float*)d_in[5];
    const float* fr     = (const float*)d_in[6];
    const float* fi     = (const float*)d_in[7];
    float* out = (float*)d_out;
    float* dec = (float*)d_ws;   // [B,R,S] = 1.6 MB (harness poisons ws anyway)

    decay_kernel<<<kB, 256, 0, stream>>>(dt, fr, fi, vm, dec);
    rda_main<<<kB * kT, 256, 0, stream>>>(seq, target, tv, vm, rel, dec, out);
}

// Round 9
// 92.366 us; speedup vs baseline: 1.1728x; 1.1728x over previous
//
#include <hip/hip_runtime.h>
#include <math.h>

// Problem constants (from reference)
constexpr int kB = 256, kT = 8, kS = 200, kR = 8, kD = 64, kF = 20;
constexpr float kW1 = 3.14159265358979323846f / 19.0f;

typedef __attribute__((ext_vector_type(8))) short s16x8;   // 8 bf16 = 4 VGPR (guide §3)
typedef __attribute__((ext_vector_type(4))) float f32x4;

union F8 { s16x8 v; unsigned short u[8]; };

// split-bf16: x = hi + lo + eps, |eps| ~ 2^-16 |x|. hi = truncate (lo absorbs
// the remainder exactly), lo = RNE.
__device__ __forceinline__ unsigned short bf_hi(float x, float& hf) {
    unsigned u = __float_as_uint(x) & 0xffff0000u;
    hf = __uint_as_float(u);
    return (unsigned short)(u >> 16);
}
__device__ __forceinline__ unsigned short bf_rne(float x) {
    unsigned v = __float_as_uint(x);
    return (unsigned short)((v + 0x7fffu + ((v >> 16) & 1u)) >> 16);
}

// ---------------------------------------------------------------------------
// Kernel 1 (unchanged from R8): decay[b][r][s] once per b into d_ws.
// ---------------------------------------------------------------------------
__global__ __launch_bounds__(256) void decay_kernel(
    const float* __restrict__ dt, const float* __restrict__ fr,
    const float* __restrict__ fi, const int* __restrict__ vm,
    float* __restrict__ dec)
{
    const int b = blockIdx.x;
    const int tid = threadIdx.x;
    const int r = tid >> 5, j = tid & 31;

    float frr[kF], fir[kF];
    {
        const float4* f4 = (const float4*)(fr + r * kF);
        const float4* g4 = (const float4*)(fi + r * kF);
#pragma unroll
        for (int c = 0; c < 5; ++c) {
            float4 a = f4[c], g = g4[c];
            frr[4*c+0]=a.x; frr[4*c+1]=a.y; frr[4*c+2]=a.z; frr[4*c+3]=a.w;
            fir[4*c+0]=g.x; fir[4*c+1]=g.y; fir[4*c+2]=g.z; fir[4*c+3]=g.w;
        }
    }
#pragma unroll
    for (int it = 0; it < 7; ++it) {
        const int s = j + 32 * it;
        if (s < kS) {
            const float tt = dt[b * kS + s];
            const bool valid = vm[b * kS + s] != 0;
            float s1, c1;
            __sincosf(kW1 * tt, &s1, &c1);
            float ck = c1, sk = s1;
            float acc = frr[0] + c1 * frr[1] - s1 * fir[1];
#pragma unroll
            for (int k = 2; k < kF; ++k) {
                float cn = ck * c1 - sk * s1;
                float sn = sk * c1 + ck * s1;
                ck = cn; sk = sn;
                acc += ck * frr[k] - sk * fir[k];
            }
            float v = fminf(fmaxf(acc * (1.0f / (2.0f * kF)), 0.f), 1.f);
            dec[(b * kR + r) * kS + s] = valid ? v : 0.f;
        }
    }
}

// ---------------------------------------------------------------------------
// Kernel 2: split-bf16 MFMA version. One block per (b, t-pair), grid 1024
// (4 blocks/CU), 256 threads = 4 waves. n = t_local*8 + r in [0,16).
//   P0    : riB[n][d] = (rel+tv)*target -> LDS bf16 hi/lo, [n][k] layout
//           (B-frag of GEMM1 = 8 contiguous k per lane, row n = lane&15)
//   GEMM1 : att_raw[n][s] = sum_d seq[s][d]*ri[n][d]
//           M=S (13 Mtiles, waves stride-4), N=16, K=64. A = seq from
//           GLOBAL (lane reads 8 contiguous d = 2 float4), split to hi/lo.
//           3 MFMA per K-tile: Ah*Bh + Ah*Bl + Al*Bh (drop lo*lo).
//           D layout (verified): col=lane&15 (n), row=(lane>>4)*4+i (s).
//   P2    : masked softmax over s per n (wave w: rows 4w..4w+3) * dec,
//           result -> LDS bf16 hi/lo [n][s], s in [200,224) zeroed (K-pad).
//   GEMM2 : out[n][d] = sum_s att_f[n][s]*seq[s][d]
//           M=16, N=64 (wave w owns d-cols 16w..16w+16), K=224.
//           B = seq from global (lane: fixed d, 8 consecutive s), A from LDS.
// LDS paddings chosen for bank spread: riB rows 72 halves (36w%32=4),
// attr rows 212 f32 (212%32=20), ath/atl rows 232 halves (116w%32=20).
// NOTES: global att.max() shift-invariant -> omitted. Plain launch_bounds
// (R5/R6: min-waves arg forces spills). Split-bf16 abs err ~2e-6 << 1.6e-5.
// ---------------------------------------------------------------------------
__global__ __launch_bounds__(256) void rda_mfma(
    const float* __restrict__ seq,    // [B,S,D]
    const float* __restrict__ target, // [B,T,D]
    const float* __restrict__ tv,     // [B,T,R,D]
    const int*   __restrict__ vm,     // [B,S]
    const float* __restrict__ rel,    // [R,D]
    const float* __restrict__ dec,    // [B,R,S] (d_ws)
    float* __restrict__ out)          // [B,T,R,D]
{
    __shared__ unsigned short riBh[16][72], riBl[16][72];  // 4.5 KB
    __shared__ float attr[16][212];                        // 13.25 KB
    __shared__ unsigned short ath[16][232], atl[16][232];  // 14.5 KB

    const int o = blockIdx.x, b = o & 255, g = o >> 8, t0 = 2 * g;
    const int tid = threadIdx.x, w = tid >> 6, l = tid & 63;
    const int lm = l & 15, lq = l >> 4;

    // ---- P0: riB (1024 values, 4 per thread)
    {
        const int n = tid >> 4, d0 = (tid & 15) * 4;
        const int tl = n >> 3, r = n & 7;
        const int btl = b * kT + t0 + tl;
        float4 rv  = *(const float4*)(rel + r * kD + d0);
        float4 tvv = *(const float4*)(tv + ((size_t)btl * kR + r) * kD + d0);
        float4 tg  = *(const float4*)(target + (size_t)btl * kD + d0);
        float x[4] = {(rv.x+tvv.x)*tg.x, (rv.y+tvv.y)*tg.y,
                      (rv.z+tvv.z)*tg.z, (rv.w+tvv.w)*tg.w};
        ushort4 h, lo; float hf;
        h.x = bf_hi(x[0], hf); lo.x = bf_rne(x[0] - hf);
        h.y = bf_hi(x[1], hf); lo.y = bf_rne(x[1] - hf);
        h.z = bf_hi(x[2], hf); lo.z = bf_rne(x[2] - hf);
        h.w = bf_hi(x[3], hf); lo.w = bf_rne(x[3] - hf);
        *(ushort4*)&riBh[n][d0] = h;
        *(ushort4*)&riBl[n][d0] = lo;
    }
    __syncthreads();

    // ---- GEMM1: scores
    for (int Mt = w; Mt < 13; Mt += 4) {
        const int srow = min(Mt * 16 + lm, kS - 1);   // clamp pad rows (unused)
        const float* sp = seq + ((size_t)b * kS + srow) * kD;
        F8 ah[2], al[2];
#pragma unroll
        for (int Kt = 0; Kt < 2; ++Kt) {
            const int d0 = Kt * 32 + lq * 8;
            float4 x0 = *(const float4*)(sp + d0);
            float4 x1 = *(const float4*)(sp + d0 + 4);
            float xs[8] = {x0.x,x0.y,x0.z,x0.w,x1.x,x1.y,x1.z,x1.w};
#pragma unroll
            for (int i = 0; i < 8; ++i) {
                float hf; ah[Kt].u[i] = bf_hi(xs[i], hf);
                al[Kt].u[i] = bf_rne(xs[i] - hf);
            }
        }
        f32x4 acc = {0.f, 0.f, 0.f, 0.f};
#pragma unroll
        for (int Kt = 0; Kt < 2; ++Kt) {
            F8 bh, bl;
            bh.v = *(const s16x8*)&riBh[lm][Kt * 32 + lq * 8];
            bl.v = *(const s16x8*)&riBl[lm][Kt * 32 + lq * 8];
            acc = __builtin_amdgcn_mfma_f32_16x16x32_bf16(ah[Kt].v, bh.v, acc, 0, 0, 0);
            acc = __builtin_amdgcn_mfma_f32_16x16x32_bf16(ah[Kt].v, bl.v, acc, 0, 0, 0);
            acc = __builtin_amdgcn_mfma_f32_16x16x32_bf16(al[Kt].v, bh.v, acc, 0, 0, 0);
        }
        *(f32x4*)&attr[lm][Mt * 16 + lq * 4] = acc;   // col n=lm, rows s=Mt*16+lq*4+i
    }
    __syncthreads();

    // ---- P2: masked softmax * dec, rows n = 4w..4w+3 -> bf16 hi/lo
    {
        bool ok0 = vm[b * kS + l] != 0;
        bool ok1 = vm[b * kS + l + 64] != 0;
        bool ok2 = vm[b * kS + l + 128] != 0;
        bool ok3 = (l < 8) && (vm[b * kS + 192 + l] != 0);
        const int s3 = (l < 8) ? 192 + l : kS - 1;
#pragma unroll
        for (int j = 0; j < 4; ++j) {
            const int n = 4 * w + j, r = n & 7;
            float a0 = ok0 ? attr[n][l]       : -INFINITY;
            float a1 = ok1 ? attr[n][l + 64]  : -INFINITY;
            float a2 = ok2 ? attr[n][l + 128] : -INFINITY;
            float a3 = ok3 ? attr[n][s3]      : -INFINITY;
            float m = fmaxf(fmaxf(a0, a1), fmaxf(a2, a3));
#pragma unroll
            for (int off = 32; off; off >>= 1) m = fmaxf(m, __shfl_xor(m, off));
            float e0 = __expf(a0 - m), e1 = __expf(a1 - m);
            float e2 = __expf(a2 - m), e3 = ok3 ? __expf(a3 - m) : 0.f;
            float ssum = e0 + e1 + e2 + e3;
#pragma unroll
            for (int off = 32; off; off >>= 1) ssum += __shfl_xor(ssum, off);
            const float inv = 1.0f / ssum;
            const float* dg = dec + ((size_t)b * kR + r) * kS;
            float p0 = e0 * inv * dg[l];
            float p1 = e1 * inv * dg[l + 64];
            float p2 = e2 * inv * dg[l + 128];
            float p3 = ok3 ? e3 * inv * dg[192 + l] : 0.f;
            float hf;
            ath[n][l]       = bf_hi(p0, hf); atl[n][l]       = bf_rne(p0 - hf);
            ath[n][l + 64]  = bf_hi(p1, hf); atl[n][l + 64]  = bf_rne(p1 - hf);
            ath[n][l + 128] = bf_hi(p2, hf); atl[n][l + 128] = bf_rne(p2 - hf);
            if (l < 32) {   // s in [192,224): real for l<8, ZERO K-pad else
                float pv = (l < 8) ? p3 : 0.f;
                ath[n][192 + l] = bf_hi(pv, hf); atl[n][192 + l] = bf_rne(pv - hf);
            }
        }
    }
    __syncthreads();

    // ---- GEMM2: context; wave w owns d-cols [16w, 16w+16)
    {
        const int dcol = w * 16 + lm;
        f32x4 acc = {0.f, 0.f, 0.f, 0.f};
        for (int Kt = 0; Kt < 7; ++Kt) {
            F8 bh, bl;
#pragma unroll
            for (int i = 0; i < 8; ++i) {
                const int s = Kt * 32 + lq * 8 + i;
                float x = (s < kS) ? seq[((size_t)b * kS + s) * kD + dcol] : 0.f;
                float hf; bh.u[i] = bf_hi(x, hf); bl.u[i] = bf_rne(x - hf);
            }
            F8 ahh, alo;
            ahh.v = *(const s16x8*)&ath[lm][Kt * 32 + lq * 8];
            alo.v = *(const s16x8*)&atl[lm][Kt * 32 + lq * 8];
            acc = __builtin_amdgcn_mfma_f32_16x16x32_bf16(ahh.v, bh.v, acc, 0, 0, 0);
            acc = __builtin_amdgcn_mfma_f32_16x16x32_bf16(ahh.v, bl.v, acc, 0, 0, 0);
            acc = __builtin_amdgcn_mfma_f32_16x16x32_bf16(alo.v, bh.v, acc, 0, 0, 0);
        }
#pragma unroll
        for (int i = 0; i < 4; ++i) {
            const int n = lq * 4 + i, tl = n >> 3, r = n & 7;
            out[(((size_t)(b * kT + t0 + tl)) * kR + r) * kD + dcol] = acc[i];
        }
    }
}

extern "C" void kernel_launch(void* const* d_in, const int* in_sizes, int n_in,
                              void* d_out, int out_size, void* d_ws, size_t ws_size,
                              hipStream_t stream) {
    const float* seq    = (const float*)d_in[0];
    const float* dt     = (const float*)d_in[1];
    const float* target = (const float*)d_in[2];
    const float* tv     = (const float*)d_in[3];
    const int*   vm     = (const int*)  d_in[4];
    const float* rel    = (const float*)d_in[5];
    const float* fr     = (const float*)d_in[6];
    const float* fi     = (const float*)d_in[7];
    float* out = (float*)d_out;
    float* dec = (float*)d_ws;   // [B,R,S] = 1.6 MB

    decay_kernel<<<kB, 256, 0, stream>>>(dt, fr, fi, vm, dec);
    rda_mfma<<<kB * 4, 256, 0, stream>>>(seq, target, tv, vm, rel, dec, out);
}